// Round 1
// baseline (1756.182 us; speedup 1.0000x reference)
//
#include <hip/hip_runtime.h>
#include <cstdint>
#include <cstddef>

#define N_NODES 4096
#define EMB 10
#define BATCH_SZ 64
#define CI 64
#define CO 64

// ---------------------------------------------------------------------------
// Kernel A: S[n,:] = softmax(relu(E[n,:] @ E^T))   (one block per row n)
// ---------------------------------------------------------------------------
__global__ __launch_bounds__(256) void support_softmax(
    const float* __restrict__ E, float* __restrict__ S) {
  __shared__ float sim[N_NODES];      // 16 KB
  __shared__ float EnS[EMB];
  __shared__ float redmax[4];
  __shared__ float redsum[4];
  const int n = blockIdx.x;
  const int t = threadIdx.x;
  if (t < EMB) EnS[t] = E[n * EMB + t];
  __syncthreads();
  float en[EMB];
#pragma unroll
  for (int d = 0; d < EMB; ++d) en[d] = EnS[d];

  float lmax = -1e30f;
  for (int m = t; m < N_NODES; m += 256) {
    const float* Em = E + m * EMB;
    float acc = 0.f;
#pragma unroll
    for (int d = 0; d < EMB; ++d) acc += en[d] * Em[d];
    acc = fmaxf(acc, 0.f);   // relu
    sim[m] = acc;
    lmax = fmaxf(lmax, acc);
  }
  lmax = fmaxf(lmax, __shfl_xor(lmax, 32));
  lmax = fmaxf(lmax, __shfl_xor(lmax, 16));
  lmax = fmaxf(lmax, __shfl_xor(lmax, 8));
  lmax = fmaxf(lmax, __shfl_xor(lmax, 4));
  lmax = fmaxf(lmax, __shfl_xor(lmax, 2));
  lmax = fmaxf(lmax, __shfl_xor(lmax, 1));
  if ((t & 63) == 0) redmax[t >> 6] = lmax;
  __syncthreads();
  const float gmax = fmaxf(fmaxf(redmax[0], redmax[1]), fmaxf(redmax[2], redmax[3]));

  float lsum = 0.f;
  for (int m = t; m < N_NODES; m += 256) {
    const float e = __expf(sim[m] - gmax);
    sim[m] = e;
    lsum += e;
  }
  lsum += __shfl_xor(lsum, 32);
  lsum += __shfl_xor(lsum, 16);
  lsum += __shfl_xor(lsum, 8);
  lsum += __shfl_xor(lsum, 4);
  lsum += __shfl_xor(lsum, 2);
  lsum += __shfl_xor(lsum, 1);
  if ((t & 63) == 0) redsum[t >> 6] = lsum;
  __syncthreads();
  const float inv = 1.0f / (redsum[0] + redsum[1] + redsum[2] + redsum[3]);

  float* Srow = S + (size_t)n * N_NODES;
  for (int m = t; m < N_NODES; m += 256) Srow[m] = sim[m] * inv;
}

// ---------------------------------------------------------------------------
// Kernel B: Z = S @ X   where X[m, j] = x[b, m, c], j = b*64 + c  (J = 4096)
// 128x128 tile per 256-thread block, BK=16, 8x8 per-thread micro-tile.
// Xs columns staggered (+4 floats every 32) to keep ds_read_b128 <=2-way.
// ---------------------------------------------------------------------------
__global__ __launch_bounds__(256) void diffuse_gemm(
    const float* __restrict__ S, const float* __restrict__ X, float* __restrict__ Z) {
  __shared__ float Ss[16][128];   // [k][n]  (A transposed)
  __shared__ float Xs[16][144];   // [k][j'] staggered columns
  const int t = threadIdx.x;
  const int n0 = blockIdx.y * 128;
  const int j0 = blockIdx.x * 128;
  const int tr8 = (t >> 4) * 8;           // output row group within tile
  const int tc = t & 15;                  // output col group
  const int c0 = tc * 8;
  const int c0s = c0 + ((c0 >> 5) << 2);  // staggered LDS column

  // staging maps
  const int sa_n = t >> 2;                // 0..63 (+64 second row)
  const int sa_k = (t & 3) * 4;
  const int sb_m = t >> 5;                // 0..7 (+8 second row)
  const int sb_c = (t & 31) * 4;
  const int sb_cs = sb_c + ((sb_c >> 5) << 2);
  const int jg = j0 + sb_c;
  const float* xcol = X + (size_t)(jg >> 6) * (N_NODES * CI) + (jg & 63);
  const float* sArow0 = S + (size_t)(n0 + sa_n) * N_NODES + sa_k;
  const float* sArow1 = S + (size_t)(n0 + sa_n + 64) * N_NODES + sa_k;

  // prologue: load tile 0 into registers
  float4 rA0 = *reinterpret_cast<const float4*>(sArow0);
  float4 rA1 = *reinterpret_cast<const float4*>(sArow1);
  float4 rB0 = *reinterpret_cast<const float4*>(xcol + (size_t)sb_m * CI);
  float4 rB1 = *reinterpret_cast<const float4*>(xcol + (size_t)(sb_m + 8) * CI);

  float acc[8][8];
#pragma unroll
  for (int u = 0; u < 8; ++u)
#pragma unroll
    for (int v = 0; v < 8; ++v) acc[u][v] = 0.f;

  for (int kt = 0; kt < N_NODES / 16; ++kt) {
    __syncthreads();
    // transpose-store S tile, direct-store X tile
    Ss[sa_k + 0][sa_n] = rA0.x; Ss[sa_k + 1][sa_n] = rA0.y;
    Ss[sa_k + 2][sa_n] = rA0.z; Ss[sa_k + 3][sa_n] = rA0.w;
    Ss[sa_k + 0][sa_n + 64] = rA1.x; Ss[sa_k + 1][sa_n + 64] = rA1.y;
    Ss[sa_k + 2][sa_n + 64] = rA1.z; Ss[sa_k + 3][sa_n + 64] = rA1.w;
    *reinterpret_cast<float4*>(&Xs[sb_m][sb_cs]) = rB0;
    *reinterpret_cast<float4*>(&Xs[sb_m + 8][sb_cs]) = rB1;
    __syncthreads();
    if (kt + 1 < N_NODES / 16) {   // prefetch next tile into registers
      const int k0 = (kt + 1) * 16;
      rA0 = *reinterpret_cast<const float4*>(sArow0 + k0);
      rA1 = *reinterpret_cast<const float4*>(sArow1 + k0);
      rB0 = *reinterpret_cast<const float4*>(xcol + (size_t)(k0 + sb_m) * CI);
      rB1 = *reinterpret_cast<const float4*>(xcol + (size_t)(k0 + sb_m + 8) * CI);
    }
#pragma unroll
    for (int k = 0; k < 16; ++k) {
      float a[8], b[8];
      *reinterpret_cast<float4*>(&a[0]) = *reinterpret_cast<const float4*>(&Ss[k][tr8]);
      *reinterpret_cast<float4*>(&a[4]) = *reinterpret_cast<const float4*>(&Ss[k][tr8 + 4]);
      *reinterpret_cast<float4*>(&b[0]) = *reinterpret_cast<const float4*>(&Xs[k][c0s]);
      *reinterpret_cast<float4*>(&b[4]) = *reinterpret_cast<const float4*>(&Xs[k][c0s + 4]);
#pragma unroll
      for (int u = 0; u < 8; ++u)
#pragma unroll
        for (int v = 0; v < 8; ++v) acc[u][v] += a[u] * b[v];
    }
  }

  // write Z (= d_out, fully overwritten): thread's 8 cols stay in one batch
  const int bb = blockIdx.x * 2 + (tc >> 3);
  const int cc = (tc & 7) * 8;
  float* zp = Z + (size_t)bb * (N_NODES * CI) + cc;
#pragma unroll
  for (int u = 0; u < 8; ++u) {
    const size_t row = (size_t)(n0 + tr8 + u) * CI;
    *reinterpret_cast<float4*>(&zp[row]) =
        make_float4(acc[u][0], acc[u][1], acc[u][2], acc[u][3]);
    *reinterpret_cast<float4*>(&zp[row + 4]) =
        make_float4(acc[u][4], acc[u][5], acc[u][6], acc[u][7]);
  }
}

// ---------------------------------------------------------------------------
// Kernel C: per-node weights + bias from pools, then
// out[b,n,o] = sum_i x[b,n,i]*W[n,0,i,o] + Z[b,n,i]*W[n,1,i,o] + bias[n,o]
// In-place on d_out (block n only touches node n's rows).
// ---------------------------------------------------------------------------
__global__ __launch_bounds__(256) void node_gemm(
    const float* __restrict__ x, const float* __restrict__ E,
    const float* __restrict__ wp, const float* __restrict__ bp,
    float* zio /* Z in, out out */) {
  __shared__ float Ws[128 * 64];     // W'[r][o], r = k*64+i   (32 KB)
  __shared__ float xzs[32 * 133];    // [b_local][r] padded    (17 KB)
  __shared__ float biasS[64];
  __shared__ float EnS[EMB];
  const int n = blockIdx.x;
  const int t = threadIdx.x;
  if (t < EMB) EnS[t] = E[n * EMB + t];
  __syncthreads();
  float en[EMB];
#pragma unroll
  for (int d = 0; d < EMB; ++d) en[d] = EnS[d];

  // W'[r][o] = sum_d en[d] * wp[d, r, o]   (wp stride 8192 per d), vectorized
  const float4* wp4 = reinterpret_cast<const float4*>(wp);
  float4* Ws4 = reinterpret_cast<float4*>(Ws);
  for (int p = 0; p < 8; ++p) {
    const int e4 = p * 256 + t;
    float4 a = make_float4(0.f, 0.f, 0.f, 0.f);
#pragma unroll
    for (int d = 0; d < EMB; ++d) {
      const float4 w = wp4[d * 2048 + e4];
      a.x += en[d] * w.x; a.y += en[d] * w.y;
      a.z += en[d] * w.z; a.w += en[d] * w.w;
    }
    Ws4[e4] = a;
  }
  if (t < CO) {
    float b = 0.f;
#pragma unroll
    for (int d = 0; d < EMB; ++d) b += en[d] * bp[d * CO + t];
    biasS[t] = b;
  }

  const int to = (t & 15) * 4;     // 4 output cols
  const int tb2 = (t >> 4) * 2;    // 2 local batch rows
  const int i = t & 63;
  const int bq = t >> 6;
  __syncthreads();                 // Ws/bias ready

  for (int bh = 0; bh < 2; ++bh) {
    // stage 32 batch rows of x (r<64) and Z (r>=64)
#pragma unroll
    for (int p = 0; p < 8; ++p) {
      const int bl = bq + p * 4;                   // 0..31
      const int b = bh * 32 + bl;
      const size_t g = (size_t)b * (N_NODES * CI) + (size_t)n * CI + i;
      xzs[bl * 133 + i] = x[g];
      xzs[bl * 133 + 64 + i] = zio[g];
    }
    __syncthreads();

    float acc[2][4];
    {
      const float4 bv = *reinterpret_cast<const float4*>(&biasS[to]);
#pragma unroll
      for (int u = 0; u < 2; ++u) {
        acc[u][0] = bv.x; acc[u][1] = bv.y; acc[u][2] = bv.z; acc[u][3] = bv.w;
      }
    }
#pragma unroll 4
    for (int r = 0; r < 128; ++r) {
      const float4 w = *reinterpret_cast<const float4*>(&Ws[r * 64 + to]);
#pragma unroll
      for (int u = 0; u < 2; ++u) {
        const float a = xzs[(tb2 + u) * 133 + r];
        acc[u][0] += a * w.x; acc[u][1] += a * w.y;
        acc[u][2] += a * w.z; acc[u][3] += a * w.w;
      }
    }
#pragma unroll
    for (int u = 0; u < 2; ++u) {
      const int b = bh * 32 + tb2 + u;
      *reinterpret_cast<float4*>(
          &zio[(size_t)b * (N_NODES * CI) + (size_t)n * CI + to]) =
          make_float4(acc[u][0], acc[u][1], acc[u][2], acc[u][3]);
    }
    __syncthreads();  // xzs consumed before next stage
  }
}

// ---------------------------------------------------------------------------
extern "C" void kernel_launch(void* const* d_in, const int* in_sizes, int n_in,
                              void* d_out, int out_size, void* d_ws, size_t ws_size,
                              hipStream_t stream) {
  const float* x  = (const float*)d_in[0];   // [64, 4096, 64]
  const float* E  = (const float*)d_in[1];   // [4096, 10]
  const float* wp = (const float*)d_in[2];   // [10, 2, 64, 64]
  const float* bp = (const float*)d_in[3];   // [10, 64]
  float* out = (float*)d_out;                // [64, 4096, 64]
  float* S = (float*)d_ws;                   // [4096, 4096]  (64 MB scratch)

  support_softmax<<<N_NODES, 256, 0, stream>>>(E, S);
  diffuse_gemm<<<dim3(32, 32), 256, 0, stream>>>(S, x, out);   // Z -> d_out
  node_gemm<<<N_NODES, 256, 0, stream>>>(x, E, wp, bp, out);   // in-place
}

// Round 2
// 438.906 us; speedup vs baseline: 4.0013x; 4.0013x over previous
//
#include <hip/hip_runtime.h>
#include <cstdint>
#include <cstddef>

#define N_NODES 4096
#define EMB 10
#define BATCH_SZ 64
#define CI 64
#define CO 64

typedef unsigned short u16;
typedef __bf16 bf16x8 __attribute__((ext_vector_type(8)));
typedef float f32x4 __attribute__((ext_vector_type(4)));

__device__ __forceinline__ u16 f2bf(float f) {
  union { float f; uint32_t u; } v; v.f = f;
  const uint32_t r = v.u + 0x7fffu + ((v.u >> 16) & 1u);  // RNE (finite inputs)
  return (u16)(r >> 16);
}

__device__ __forceinline__ void gload16(const void* g, void* l) {
  __builtin_amdgcn_global_load_lds(
      (__attribute__((address_space(1))) void*)(g),
      (__attribute__((address_space(3))) void*)(l), 16, 0, 0);
}

// ---------------------------------------------------------------------------
// Kernel A: S[n,:] = softmax(relu(E[n,:] @ E^T))  -> bf16   (one block per row)
// ---------------------------------------------------------------------------
__global__ __launch_bounds__(256) void support_softmax(
    const float* __restrict__ E, u16* __restrict__ Sb) {
  __shared__ float sim[N_NODES];      // 16 KB
  __shared__ float EnS[EMB];
  __shared__ float redmax[4];
  __shared__ float redsum[4];
  const int n = blockIdx.x;
  const int t = threadIdx.x;
  if (t < EMB) EnS[t] = E[n * EMB + t];
  __syncthreads();
  float en[EMB];
#pragma unroll
  for (int d = 0; d < EMB; ++d) en[d] = EnS[d];

  float lmax = -1e30f;
  for (int m = t; m < N_NODES; m += 256) {
    const float* Em = E + m * EMB;
    float acc = 0.f;
#pragma unroll
    for (int d = 0; d < EMB; ++d) acc += en[d] * Em[d];
    acc = fmaxf(acc, 0.f);   // relu
    sim[m] = acc;
    lmax = fmaxf(lmax, acc);
  }
  lmax = fmaxf(lmax, __shfl_xor(lmax, 32));
  lmax = fmaxf(lmax, __shfl_xor(lmax, 16));
  lmax = fmaxf(lmax, __shfl_xor(lmax, 8));
  lmax = fmaxf(lmax, __shfl_xor(lmax, 4));
  lmax = fmaxf(lmax, __shfl_xor(lmax, 2));
  lmax = fmaxf(lmax, __shfl_xor(lmax, 1));
  if ((t & 63) == 0) redmax[t >> 6] = lmax;
  __syncthreads();
  const float gmax = fmaxf(fmaxf(redmax[0], redmax[1]), fmaxf(redmax[2], redmax[3]));

  float lsum = 0.f;
  for (int m = t; m < N_NODES; m += 256) {
    const float e = __expf(sim[m] - gmax);
    sim[m] = e;
    lsum += e;
  }
  lsum += __shfl_xor(lsum, 32);
  lsum += __shfl_xor(lsum, 16);
  lsum += __shfl_xor(lsum, 8);
  lsum += __shfl_xor(lsum, 4);
  lsum += __shfl_xor(lsum, 2);
  lsum += __shfl_xor(lsum, 1);
  if ((t & 63) == 0) redsum[t >> 6] = lsum;
  __syncthreads();
  const float inv = 1.0f / (redsum[0] + redsum[1] + redsum[2] + redsum[3]);

  u16* Srow = Sb + (size_t)n * N_NODES;
  for (int m = t; m < N_NODES; m += 256) Srow[m] = f2bf(sim[m] * inv);
}

// ---------------------------------------------------------------------------
// Kernel A2: Xt[j][m] = bf16(x[b][m][c]),  j = b*64 + c   (B^T layout, K-contig)
// block = (b, m-tile of 64); LDS transpose keeps both sides coalesced.
// ---------------------------------------------------------------------------
__global__ __launch_bounds__(256) void convert_x(
    const float* __restrict__ x, u16* __restrict__ Xt) {
  __shared__ float sm[64][65];
  const int b = blockIdx.x, mt = blockIdx.y;
  const int t = threadIdx.x;
  const int c = t & 63, q = t >> 6;
  const float* xp = x + ((size_t)b * N_NODES + mt * 64) * CI;
#pragma unroll
  for (int p = 0; p < 16; ++p) {
    const int r = q + p * 4;
    sm[r][c] = xp[(size_t)r * CI + c];
  }
  __syncthreads();
  u16* op = Xt + (size_t)(b * 64) * N_NODES + mt * 64;
#pragma unroll
  for (int p = 0; p < 16; ++p) {
    const int cc = q + p * 4;                    // channel index -> Xt row
    op[(size_t)cc * N_NODES + c] = f2bf(sm[c][cc]);
  }
}

// ---------------------------------------------------------------------------
// Kernel B: Z = S @ Xt^T via bf16 MFMA (m97 structure).
// 128x128 tile, BK=32, 4 waves (2x2), each wave 64x64 out = 4x4 frags of
// 16x16x32.  LDS tiles [128][32] bf16 are conflict-free for this frag pattern.
// ---------------------------------------------------------------------------
__global__ __launch_bounds__(256) void diffuse_gemm_mfma(
    const u16* __restrict__ S, const u16* __restrict__ Xt,
    float* __restrict__ Z) {
  __shared__ __align__(16) u16 As[128 * 32];   // 8 KB  [row n][k]
  __shared__ __align__(16) u16 Bs[128 * 32];   // 8 KB  [row j][k]
  const int t = threadIdx.x;
  const int lane = t & 63;
  const int w = t >> 6;                 // wave 0..3
  const int wm = w >> 1, wn = w & 1;    // 2x2 wave grid
  const int n0 = blockIdx.y * 128;
  const int j0 = blockIdx.x * 128;

  // staging: wave w owns rows [w*32, w*32+32); 2 instrs x 16 rows each
  const int srow = w * 32 + (lane >> 2);
  const int schunk = (lane & 3) * 8;    // bf16 elems within a 32-elem row
  const u16* gA = S  + (size_t)(n0 + srow) * N_NODES + schunk;
  const u16* gB = Xt + (size_t)(j0 + srow) * N_NODES + schunk;
  u16* lA = &As[(w * 32) * 32];
  u16* lB = &Bs[(w * 32) * 32];

  f32x4 acc[4][4];
#pragma unroll
  for (int i = 0; i < 4; ++i)
#pragma unroll
    for (int j = 0; j < 4; ++j) acc[i][j] = (f32x4)0.f;

  const int fr = lane & 15;             // frag row (A) / col (B)
  const int fk = (lane >> 4) * 8;       // k-element offset
  const int aoff = (wm * 64 + fr) * 32 + fk;
  const int boff = (wn * 64 + fr) * 32 + fk;

  for (int kt = 0; kt < N_NODES / 32; ++kt) {
    const size_t ko = (size_t)kt * 32;
    gload16(gA + ko, lA);
    gload16(gA + ko + (size_t)16 * N_NODES, lA + 16 * 32);
    gload16(gB + ko, lB);
    gload16(gB + ko + (size_t)16 * N_NODES, lB + 16 * 32);
    __syncthreads();                    // vmcnt(0) drain + barrier
    bf16x8 a[4], b[4];
#pragma unroll
    for (int fm = 0; fm < 4; ++fm)
      a[fm] = *reinterpret_cast<const bf16x8*>(&As[aoff + fm * 16 * 32]);
#pragma unroll
    for (int fn = 0; fn < 4; ++fn)
      b[fn] = *reinterpret_cast<const bf16x8*>(&Bs[boff + fn * 16 * 32]);
#pragma unroll
    for (int fm = 0; fm < 4; ++fm)
#pragma unroll
      for (int fn = 0; fn < 4; ++fn)
        acc[fm][fn] = __builtin_amdgcn_mfma_f32_16x16x32_bf16(
            a[fm], b[fn], acc[fm][fn], 0, 0, 0);
    __syncthreads();                    // tile consumed before next stage
  }

  // epilogue: C/D layout col=lane&15, row=(lane>>4)*4+reg  [m89-verified]
  const int crow = (lane >> 4) * 4;
  const int ccol = lane & 15;
  const int bb = (j0 >> 6) + wn;        // batch index
  float* zb = Z + (size_t)bb * (N_NODES * CI);
#pragma unroll
  for (int fm = 0; fm < 4; ++fm) {
    const int nrow = n0 + wm * 64 + fm * 16 + crow;
#pragma unroll
    for (int fn = 0; fn < 4; ++fn) {
      const int cout = fn * 16 + ccol;
#pragma unroll
      for (int r = 0; r < 4; ++r)
        zb[(size_t)(nrow + r) * CI + cout] = acc[fm][fn][r];
    }
  }
}

// ---------------------------------------------------------------------------
// Kernel C: per-node weights + bias from pools, then
// out[b,n,o] = sum_i x[b,n,i]*W[n,0,i,o] + Z[b,n,i]*W[n,1,i,o] + bias[n,o]
// In-place on d_out (block n only touches node n's rows).
// ---------------------------------------------------------------------------
__global__ __launch_bounds__(256) void node_gemm(
    const float* __restrict__ x, const float* __restrict__ E,
    const float* __restrict__ wp, const float* __restrict__ bp,
    float* zio /* Z in, out out */) {
  __shared__ float Ws[128 * 64];     // W'[r][o], r = k*64+i   (32 KB)
  __shared__ float xzs[32 * 133];    // [b_local][r] padded    (17 KB)
  __shared__ float biasS[64];
  __shared__ float EnS[EMB];
  const int n = blockIdx.x;
  const int t = threadIdx.x;
  if (t < EMB) EnS[t] = E[n * EMB + t];
  __syncthreads();
  float en[EMB];
#pragma unroll
  for (int d = 0; d < EMB; ++d) en[d] = EnS[d];

  const float4* wp4 = reinterpret_cast<const float4*>(wp);
  float4* Ws4 = reinterpret_cast<float4*>(Ws);
  for (int p = 0; p < 8; ++p) {
    const int e4 = p * 256 + t;
    float4 a = make_float4(0.f, 0.f, 0.f, 0.f);
#pragma unroll
    for (int d = 0; d < EMB; ++d) {
      const float4 w = wp4[d * 2048 + e4];
      a.x += en[d] * w.x; a.y += en[d] * w.y;
      a.z += en[d] * w.z; a.w += en[d] * w.w;
    }
    Ws4[e4] = a;
  }
  if (t < CO) {
    float b = 0.f;
#pragma unroll
    for (int d = 0; d < EMB; ++d) b += en[d] * bp[d * CO + t];
    biasS[t] = b;
  }

  const int to = (t & 15) * 4;     // 4 output cols
  const int tb2 = (t >> 4) * 2;    // 2 local batch rows
  const int i = t & 63;
  const int bq = t >> 6;
  __syncthreads();                 // Ws/bias ready

  for (int bh = 0; bh < 2; ++bh) {
#pragma unroll
    for (int p = 0; p < 8; ++p) {
      const int bl = bq + p * 4;                   // 0..31
      const int b = bh * 32 + bl;
      const size_t g = (size_t)b * (N_NODES * CI) + (size_t)n * CI + i;
      xzs[bl * 133 + i] = x[g];
      xzs[bl * 133 + 64 + i] = zio[g];
    }
    __syncthreads();

    float acc[2][4];
    {
      const float4 bv = *reinterpret_cast<const float4*>(&biasS[to]);
#pragma unroll
      for (int u = 0; u < 2; ++u) {
        acc[u][0] = bv.x; acc[u][1] = bv.y; acc[u][2] = bv.z; acc[u][3] = bv.w;
      }
    }
#pragma unroll 4
    for (int r = 0; r < 128; ++r) {
      const float4 w = *reinterpret_cast<const float4*>(&Ws[r * 64 + to]);
#pragma unroll
      for (int u = 0; u < 2; ++u) {
        const float a = xzs[(tb2 + u) * 133 + r];
        acc[u][0] += a * w.x; acc[u][1] += a * w.y;
        acc[u][2] += a * w.z; acc[u][3] += a * w.w;
      }
    }
#pragma unroll
    for (int u = 0; u < 2; ++u) {
      const int b = bh * 32 + tb2 + u;
      *reinterpret_cast<float4*>(
          &zio[(size_t)b * (N_NODES * CI) + (size_t)n * CI + to]) =
          make_float4(acc[u][0], acc[u][1], acc[u][2], acc[u][3]);
    }
    __syncthreads();
  }
}

// ---------------------------------------------------------------------------
extern "C" void kernel_launch(void* const* d_in, const int* in_sizes, int n_in,
                              void* d_out, int out_size, void* d_ws, size_t ws_size,
                              hipStream_t stream) {
  const float* x  = (const float*)d_in[0];   // [64, 4096, 64]
  const float* E  = (const float*)d_in[1];   // [4096, 10]
  const float* wp = (const float*)d_in[2];   // [10, 2, 64, 64]
  const float* bp = (const float*)d_in[3];   // [10, 64]
  float* out = (float*)d_out;                // [64, 4096, 64]
  u16* Sb = (u16*)d_ws;                                   // 33.5 MB bf16 S
  u16* Xt = (u16*)((char*)d_ws + (size_t)N_NODES * N_NODES * sizeof(u16));

  support_softmax<<<N_NODES, 256, 0, stream>>>(E, Sb);
  convert_x<<<dim3(BATCH_SZ, N_NODES / 64), 256, 0, stream>>>(x, Xt);
  diffuse_gemm_mfma<<<dim3(32, 32), 256, 0, stream>>>(Sb, Xt, out);  // Z -> d_out
  node_gemm<<<N_NODES, 256, 0, stream>>>(x, E, wp, bp, out);         // in-place
}

// Round 3
// 360.474 us; speedup vs baseline: 4.8719x; 1.2176x over previous
//
#include <hip/hip_runtime.h>
#include <cstdint>
#include <cstddef>

#define N_NODES 4096
#define EMB 10
#define BATCH_SZ 64
#define CI 64
#define CO 64
#define LKP 136   // 128 + 8 pad: frag ds_read_b128 lands 2-way (free)

typedef unsigned short u16;
typedef __bf16 bf16x8 __attribute__((ext_vector_type(8)));
typedef float f32x4 __attribute__((ext_vector_type(4)));

__device__ __forceinline__ u16 f2bf(float f) {
  union { float f; uint32_t u; } v; v.f = f;
  const uint32_t r = v.u + 0x7fffu + ((v.u >> 16) & 1u);  // RNE (finite inputs)
  return (u16)(r >> 16);
}

__device__ __forceinline__ void gload16(const void* g, void* l) {
  __builtin_amdgcn_global_load_lds(
      (__attribute__((address_space(1))) void*)(g),
      (__attribute__((address_space(3))) void*)(l), 16, 0, 0);
}

// ---------------------------------------------------------------------------
// Kernel A: S[n,:] = softmax(relu(E[n,:] @ E^T)) -> bf16.  4 rows per block:
// E is read once per block (164 MB L2 total vs 655 MB at 1 row/block).
// ---------------------------------------------------------------------------
__global__ __launch_bounds__(256) void support_softmax(
    const float* __restrict__ E, u16* __restrict__ Sb) {
  __shared__ float sim[4][N_NODES];   // 64 KB
  __shared__ float EnS[4][EMB];
  __shared__ float red[4][4];
  const int n0 = blockIdx.x * 4;
  const int t = threadIdx.x;
  const int wid = t >> 6;
  if (t < 4 * EMB) EnS[t / EMB][t % EMB] = E[n0 * EMB + t];
  __syncthreads();
  float en[4][EMB];
#pragma unroll
  for (int r = 0; r < 4; ++r)
#pragma unroll
    for (int d = 0; d < EMB; ++d) en[r][d] = EnS[r][d];

  float rmax[4] = {-1e30f, -1e30f, -1e30f, -1e30f};
  for (int p = 0; p < 16; ++p) {
    const int m = p * 256 + t;
    const float2* e2 = reinterpret_cast<const float2*>(E + m * EMB);
    float em[EMB];
    const float2 v0 = e2[0], v1 = e2[1], v2 = e2[2], v3 = e2[3], v4 = e2[4];
    em[0] = v0.x; em[1] = v0.y; em[2] = v1.x; em[3] = v1.y; em[4] = v2.x;
    em[5] = v2.y; em[6] = v3.x; em[7] = v3.y; em[8] = v4.x; em[9] = v4.y;
#pragma unroll
    for (int r = 0; r < 4; ++r) {
      float acc = 0.f;
#pragma unroll
      for (int d = 0; d < EMB; ++d) acc += en[r][d] * em[d];
      acc = fmaxf(acc, 0.f);
      sim[r][m] = acc;
      rmax[r] = fmaxf(rmax[r], acc);
    }
  }
#pragma unroll
  for (int r = 0; r < 4; ++r) {
#pragma unroll
    for (int s = 32; s; s >>= 1) rmax[r] = fmaxf(rmax[r], __shfl_xor(rmax[r], s));
  }
  if ((t & 63) == 0) {
#pragma unroll
    for (int r = 0; r < 4; ++r) red[r][wid] = rmax[r];
  }
  __syncthreads();
  float gmax[4];
#pragma unroll
  for (int r = 0; r < 4; ++r)
    gmax[r] = fmaxf(fmaxf(red[r][0], red[r][1]), fmaxf(red[r][2], red[r][3]));
  __syncthreads();   // red re-used for sums

  float rsum[4] = {0.f, 0.f, 0.f, 0.f};
  for (int p = 0; p < 16; ++p) {
    const int m = p * 256 + t;
#pragma unroll
    for (int r = 0; r < 4; ++r) {
      const float e = __expf(sim[r][m] - gmax[r]);
      sim[r][m] = e;
      rsum[r] += e;
    }
  }
#pragma unroll
  for (int r = 0; r < 4; ++r) {
#pragma unroll
    for (int s = 32; s; s >>= 1) rsum[r] += __shfl_xor(rsum[r], s);
  }
  if ((t & 63) == 0) {
#pragma unroll
    for (int r = 0; r < 4; ++r) red[r][wid] = rsum[r];
  }
  __syncthreads();
  float inv[4];
#pragma unroll
  for (int r = 0; r < 4; ++r)
    inv[r] = 1.0f / (red[r][0] + red[r][1] + red[r][2] + red[r][3]);

  for (int p = 0; p < 16; ++p) {
    const int m = p * 256 + t;
#pragma unroll
    for (int r = 0; r < 4; ++r)
      Sb[(size_t)(n0 + r) * N_NODES + m] = f2bf(sim[r][m] * inv[r]);
  }
}

// ---------------------------------------------------------------------------
// Kernel A2: Xt[j][m] = bf16(x[b][m][c]),  j = b*64 + c  (B^T layout, K-contig)
// ---------------------------------------------------------------------------
__global__ __launch_bounds__(256) void convert_x(
    const float* __restrict__ x, u16* __restrict__ Xt) {
  __shared__ float sm[64][65];
  const int b = blockIdx.x, mt = blockIdx.y;
  const int t = threadIdx.x;
  const int c = t & 63, q = t >> 6;
  const float* xp = x + ((size_t)b * N_NODES + mt * 64) * CI;
#pragma unroll
  for (int p = 0; p < 16; ++p) {
    const int r = q + p * 4;
    sm[r][c] = xp[(size_t)r * CI + c];
  }
  __syncthreads();
  u16* op = Xt + (size_t)(b * 64) * N_NODES + mt * 64;
#pragma unroll
  for (int p = 0; p < 16; ++p) {
    const int cc = q + p * 4;
    op[(size_t)cc * N_NODES + c] = f2bf(sm[c][cc]);
  }
}

// ---------------------------------------------------------------------------
// Kernel B: Zb = S @ Xt^T via bf16 MFMA (m97 structure, BK=64).
// 128x128 tile, 4 waves (2x2), wave = 64x64 out = 4x4 frags of 16x16x32.
// Output bf16, node-major: Zb[n][j], j = b*64+c.
// ---------------------------------------------------------------------------
__global__ __launch_bounds__(256) void diffuse_gemm_mfma(
    const u16* __restrict__ S, const u16* __restrict__ Xt,
    u16* __restrict__ Zb) {
  __shared__ __align__(16) u16 As[128 * 64];   // 16 KB  [row n][k]
  __shared__ __align__(16) u16 Bs[128 * 64];   // 16 KB  [row j][k]
  const int t = threadIdx.x;
  const int lane = t & 63;
  const int w = t >> 6;
  const int wm = w >> 1, wn = w & 1;
  const int n0 = blockIdx.y * 128;
  const int j0 = blockIdx.x * 128;

  // staging: wave w stages rows [w*32, w*32+32); each gload16 covers 8 rows
  const int srow = w * 32 + (lane >> 3);
  const int scol = (lane & 7) * 8;             // bf16 elems within a 64-elem row
  const u16* gA = S  + (size_t)(n0 + srow) * N_NODES + scol;
  const u16* gB = Xt + (size_t)(j0 + srow) * N_NODES + scol;
  u16* lA = &As[(w * 32) * 64];
  u16* lB = &Bs[(w * 32) * 64];

  f32x4 acc[4][4];
#pragma unroll
  for (int i = 0; i < 4; ++i)
#pragma unroll
    for (int j = 0; j < 4; ++j) acc[i][j] = (f32x4)0.f;

  const int fr = lane & 15;
  const int fk = (lane >> 4) * 8;

  for (int kt = 0; kt < N_NODES / 64; ++kt) {
    const size_t ko = (size_t)kt * 64;
#pragma unroll
    for (int q = 0; q < 4; ++q) {
      gload16(gA + ko + (size_t)(q * 8) * N_NODES, lA + q * 512);
      gload16(gB + ko + (size_t)(q * 8) * N_NODES, lB + q * 512);
    }
    __syncthreads();                 // vmcnt(0) drain + barrier
#pragma unroll
    for (int ks = 0; ks < 2; ++ks) {
      bf16x8 a[4], b[4];
#pragma unroll
      for (int fm = 0; fm < 4; ++fm)
        a[fm] = *reinterpret_cast<const bf16x8*>(
            &As[(wm * 64 + fm * 16 + fr) * 64 + ks * 32 + fk]);
#pragma unroll
      for (int fn = 0; fn < 4; ++fn)
        b[fn] = *reinterpret_cast<const bf16x8*>(
            &Bs[(wn * 64 + fn * 16 + fr) * 64 + ks * 32 + fk]);
#pragma unroll
      for (int fm = 0; fm < 4; ++fm)
#pragma unroll
        for (int fn = 0; fn < 4; ++fn)
          acc[fm][fn] = __builtin_amdgcn_mfma_f32_16x16x32_bf16(
              a[fm], b[fn], acc[fm][fn], 0, 0, 0);
    }
    __syncthreads();
  }

  // epilogue: C/D layout col=lane&15, row=(lane>>4)*4+reg  [m89-verified]
  const int crow = (lane >> 4) * 4;
  const int ccol = lane & 15;
#pragma unroll
  for (int fm = 0; fm < 4; ++fm) {
    const int nrow = n0 + wm * 64 + fm * 16 + crow;
#pragma unroll
    for (int fn = 0; fn < 4; ++fn) {
      const int jcol = j0 + wn * 64 + fn * 16 + ccol;
#pragma unroll
      for (int r = 0; r < 4; ++r)
        Zb[(size_t)(nrow + r) * N_NODES + jcol] = f2bf(acc[fm][fn][r]);
    }
  }
}

// ---------------------------------------------------------------------------
// Kernel C: per-node MFMA GEMM. 2 nodes/block; W[n] = sum_d E[n,d]*wp[d]
// generated once per block (bf16, transposed [o][ki] in LDS); A = [x | Z]
// bf16 in LDS; out[b,n,o] = A @ W + bias, fp32.
// ---------------------------------------------------------------------------
__global__ __launch_bounds__(256) void node_gemm_mfma(
    const float* __restrict__ x, const u16* __restrict__ Zb,
    const float* __restrict__ E, const float* __restrict__ wp,
    const float* __restrict__ bp, float* __restrict__ out) {
  __shared__ __align__(16) u16 Wt[2][64][LKP];    // [node][o][ki]
  __shared__ __align__(16) u16 Axz[2][64][LKP];   // [node][b][r]  r=k*64+i
  __shared__ float biasS[2][64];
  __shared__ float EnS[2][EMB];
  const int n0 = blockIdx.x * 2;
  const int t = threadIdx.x;
  const int lane = t & 63;
  const int w = t >> 6;
  if (t < 2 * EMB) EnS[t / EMB][t % EMB] = E[n0 * EMB + t];
  __syncthreads();
  float en0[EMB], en1[EMB];
#pragma unroll
  for (int d = 0; d < EMB; ++d) { en0[d] = EnS[0][d]; en1[d] = EnS[1][d]; }

  if (t < 128) {
    const int nn = t >> 6, o = t & 63;
    float b = 0.f;
#pragma unroll
    for (int d = 0; d < EMB; ++d) b += EnS[nn][d] * bp[d * CO + o];
    biasS[nn][o] = b;
  }

  // W gen: wp element (d, ki, o) = wp[d*8192 + ki*64 + o]; float4 over o.
  const float4* wp4 = reinterpret_cast<const float4*>(wp);
#pragma unroll
  for (int p = 0; p < 8; ++p) {
    const int e4 = p * 256 + t;          // 0..2047
    const int ki = e4 >> 4, o4 = e4 & 15;
    float a0x = 0.f, a0y = 0.f, a0z = 0.f, a0w = 0.f;
    float a1x = 0.f, a1y = 0.f, a1z = 0.f, a1w = 0.f;
#pragma unroll
    for (int d = 0; d < EMB; ++d) {
      const float4 wv = wp4[d * 2048 + e4];
      a0x += en0[d] * wv.x; a0y += en0[d] * wv.y;
      a0z += en0[d] * wv.z; a0w += en0[d] * wv.w;
      a1x += en1[d] * wv.x; a1y += en1[d] * wv.y;
      a1z += en1[d] * wv.z; a1w += en1[d] * wv.w;
    }
    // transposed stores: Wt[nn][o][ki]
    Wt[0][o4 * 4 + 0][ki] = f2bf(a0x); Wt[0][o4 * 4 + 1][ki] = f2bf(a0y);
    Wt[0][o4 * 4 + 2][ki] = f2bf(a0z); Wt[0][o4 * 4 + 3][ki] = f2bf(a0w);
    Wt[1][o4 * 4 + 0][ki] = f2bf(a1x); Wt[1][o4 * 4 + 1][ki] = f2bf(a1y);
    Wt[1][o4 * 4 + 2][ki] = f2bf(a1z); Wt[1][o4 * 4 + 3][ki] = f2bf(a1w);
  }

  // stage x (r = 0..63) and Z (r = 64..127), bf16
#pragma unroll
  for (int nn = 0; nn < 2; ++nn) {
    const int ng = n0 + nn;
#pragma unroll
    for (int pb = 0; pb < 4; ++pb) {
      const int b = pb * 16 + (t >> 4);
      const int i0 = (t & 15) * 4;
      const float4 xv = *reinterpret_cast<const float4*>(
          &x[(size_t)b * (N_NODES * CI) + (size_t)ng * CI + i0]);
      ushort4 uv;
      uv.x = f2bf(xv.x); uv.y = f2bf(xv.y); uv.z = f2bf(xv.z); uv.w = f2bf(xv.w);
      *reinterpret_cast<ushort4*>(&Axz[nn][b][i0]) = uv;
    }
#pragma unroll
    for (int pz = 0; pz < 4; ++pz) {
      const int t4 = pz * 256 + t;       // 0..1023
      const int b = t4 >> 4, c0 = (t4 & 15) * 4;
      const ushort4 zv = *reinterpret_cast<const ushort4*>(
          &Zb[(size_t)ng * N_NODES + t4 * 4]);
      *reinterpret_cast<ushort4*>(&Axz[nn][b][64 + c0]) = zv;
    }
  }
  __syncthreads();

  // MFMA: wave w -> node (w>>1), batch-half (w&1)*32.  M=32,N=64,K=128.
  const int nn = w >> 1, bh = w & 1;
  const int fr = lane & 15, fk = (lane >> 4) * 8;
  f32x4 acc[2][4];
#pragma unroll
  for (int m = 0; m < 2; ++m)
#pragma unroll
    for (int n = 0; n < 4; ++n) acc[m][n] = (f32x4)0.f;

#pragma unroll
  for (int kk = 0; kk < 4; ++kk) {
    bf16x8 a[2], b[4];
#pragma unroll
    for (int m = 0; m < 2; ++m)
      a[m] = *reinterpret_cast<const bf16x8*>(
          &Axz[nn][bh * 32 + m * 16 + fr][kk * 32 + fk]);
#pragma unroll
    for (int n = 0; n < 4; ++n)
      b[n] = *reinterpret_cast<const bf16x8*>(
          &Wt[nn][n * 16 + fr][kk * 32 + fk]);
#pragma unroll
    for (int m = 0; m < 2; ++m)
#pragma unroll
      for (int n = 0; n < 4; ++n)
        acc[m][n] = __builtin_amdgcn_mfma_f32_16x16x32_bf16(
            a[m], b[n], acc[m][n], 0, 0, 0);
  }

  const int crow = (lane >> 4) * 4;
  const int ccol = lane & 15;
  const int ng = n0 + nn;
#pragma unroll
  for (int m = 0; m < 2; ++m) {
#pragma unroll
    for (int n = 0; n < 4; ++n) {
      const int o = n * 16 + ccol;
      const float bv = biasS[nn][o];
#pragma unroll
      for (int r = 0; r < 4; ++r) {
        const int b = bh * 32 + m * 16 + crow + r;
        out[(size_t)b * (N_NODES * CI) + (size_t)ng * CI + o] =
            acc[m][n][r] + bv;
      }
    }
  }
}

// ---------------------------------------------------------------------------
extern "C" void kernel_launch(void* const* d_in, const int* in_sizes, int n_in,
                              void* d_out, int out_size, void* d_ws, size_t ws_size,
                              hipStream_t stream) {
  const float* x  = (const float*)d_in[0];   // [64, 4096, 64]
  const float* E  = (const float*)d_in[1];   // [4096, 10]
  const float* wp = (const float*)d_in[2];   // [10, 2, 64, 64]
  const float* bp = (const float*)d_in[3];   // [10, 64]
  float* out = (float*)d_out;                // [64, 4096, 64]
  const size_t MAT = (size_t)N_NODES * N_NODES;   // 16.8M elems
  u16* Sb = (u16*)d_ws;                           // bf16 S      (33.5 MB)
  u16* Xt = Sb + MAT;                             // bf16 X^T    (33.5 MB)
  u16* Zb = Xt + MAT;                             // bf16 Z      (33.5 MB)

  support_softmax<<<N_NODES / 4, 256, 0, stream>>>(E, Sb);
  convert_x<<<dim3(BATCH_SZ, N_NODES / 64), 256, 0, stream>>>(x, Xt);
  diffuse_gemm_mfma<<<dim3(32, 32), 256, 0, stream>>>(Sb, Xt, Zb);
  node_gemm_mfma<<<N_NODES / 2, 256, 0, stream>>>(x, Zb, E, wp, bp, out);
}

// Round 4
// 322.843 us; speedup vs baseline: 5.4397x; 1.1166x over previous
//
#include <hip/hip_runtime.h>
#include <cstdint>
#include <cstddef>

#define N_NODES 4096
#define EMB 10
#define BATCH_SZ 64
#define CI 64
#define CO 64
#define LKP 136   // node_gemm pad

// diffuse GEMM geometry
#define BM 256
#define BN 128
#define SLOT_U16 24576   // 48 KB slot in u16
#define BOFF_U16 16384   // B-region offset within slot (32 KB)

typedef unsigned short u16;
typedef __bf16 bf16x8 __attribute__((ext_vector_type(8)));
typedef float f32x4 __attribute__((ext_vector_type(4)));

__device__ __forceinline__ u16 f2bf(float f) {
  union { float f; uint32_t u; } v; v.f = f;
  const uint32_t r = v.u + 0x7fffu + ((v.u >> 16) & 1u);  // RNE (finite inputs)
  return (u16)(r >> 16);
}

__device__ __forceinline__ void gload16(const void* g, void* l) {
  __builtin_amdgcn_global_load_lds(
      (__attribute__((address_space(1))) void*)(g),
      (__attribute__((address_space(3))) void*)(l), 16, 0, 0);
}

// ---------------------------------------------------------------------------
// Kernel A: S[n,:] = softmax(relu(E[n,:] @ E^T)) -> bf16.  4 rows per block.
// ---------------------------------------------------------------------------
__global__ __launch_bounds__(256) void support_softmax(
    const float* __restrict__ E, u16* __restrict__ Sb) {
  __shared__ float sim[4][N_NODES];   // 64 KB
  __shared__ float EnS[4][EMB];
  __shared__ float red[4][4];
  const int n0 = blockIdx.x * 4;
  const int t = threadIdx.x;
  const int wid = t >> 6;
  if (t < 4 * EMB) EnS[t / EMB][t % EMB] = E[n0 * EMB + t];
  __syncthreads();
  float en[4][EMB];
#pragma unroll
  for (int r = 0; r < 4; ++r)
#pragma unroll
    for (int d = 0; d < EMB; ++d) en[r][d] = EnS[r][d];

  float rmax[4] = {-1e30f, -1e30f, -1e30f, -1e30f};
  for (int p = 0; p < 16; ++p) {
    const int m = p * 256 + t;
    const float2* e2 = reinterpret_cast<const float2*>(E + m * EMB);
    float em[EMB];
    const float2 v0 = e2[0], v1 = e2[1], v2 = e2[2], v3 = e2[3], v4 = e2[4];
    em[0] = v0.x; em[1] = v0.y; em[2] = v1.x; em[3] = v1.y; em[4] = v2.x;
    em[5] = v2.y; em[6] = v3.x; em[7] = v3.y; em[8] = v4.x; em[9] = v4.y;
#pragma unroll
    for (int r = 0; r < 4; ++r) {
      float acc = 0.f;
#pragma unroll
      for (int d = 0; d < EMB; ++d) acc += en[r][d] * em[d];
      acc = fmaxf(acc, 0.f);
      sim[r][m] = acc;
      rmax[r] = fmaxf(rmax[r], acc);
    }
  }
#pragma unroll
  for (int r = 0; r < 4; ++r) {
#pragma unroll
    for (int s = 32; s; s >>= 1) rmax[r] = fmaxf(rmax[r], __shfl_xor(rmax[r], s));
  }
  if ((t & 63) == 0) {
#pragma unroll
    for (int r = 0; r < 4; ++r) red[r][wid] = rmax[r];
  }
  __syncthreads();
  float gmax[4];
#pragma unroll
  for (int r = 0; r < 4; ++r)
    gmax[r] = fmaxf(fmaxf(red[r][0], red[r][1]), fmaxf(red[r][2], red[r][3]));
  __syncthreads();

  float rsum[4] = {0.f, 0.f, 0.f, 0.f};
  for (int p = 0; p < 16; ++p) {
    const int m = p * 256 + t;
#pragma unroll
    for (int r = 0; r < 4; ++r) {
      const float e = __expf(sim[r][m] - gmax[r]);
      sim[r][m] = e;
      rsum[r] += e;
    }
  }
#pragma unroll
  for (int r = 0; r < 4; ++r) {
#pragma unroll
    for (int s = 32; s; s >>= 1) rsum[r] += __shfl_xor(rsum[r], s);
  }
  if ((t & 63) == 0) {
#pragma unroll
    for (int r = 0; r < 4; ++r) red[r][wid] = rsum[r];
  }
  __syncthreads();
  float inv[4];
#pragma unroll
  for (int r = 0; r < 4; ++r)
    inv[r] = 1.0f / (red[r][0] + red[r][1] + red[r][2] + red[r][3]);

  for (int p = 0; p < 16; ++p) {
    const int m = p * 256 + t;
#pragma unroll
    for (int r = 0; r < 4; ++r)
      Sb[(size_t)(n0 + r) * N_NODES + m] = f2bf(sim[r][m] * inv[r]);
  }
}

// ---------------------------------------------------------------------------
// Kernel A2: Xt[j][m] = bf16(x[b][m][c]),  j = b*64 + c
// ---------------------------------------------------------------------------
__global__ __launch_bounds__(256) void convert_x(
    const float* __restrict__ x, u16* __restrict__ Xt) {
  __shared__ float sm[64][65];
  const int b = blockIdx.x, mt = blockIdx.y;
  const int t = threadIdx.x;
  const int c = t & 63, q = t >> 6;
  const float* xp = x + ((size_t)b * N_NODES + mt * 64) * CI;
#pragma unroll
  for (int p = 0; p < 16; ++p) {
    const int r = q + p * 4;
    sm[r][c] = xp[(size_t)r * CI + c];
  }
  __syncthreads();
  u16* op = Xt + (size_t)(b * 64) * N_NODES + mt * 64;
#pragma unroll
  for (int p = 0; p < 16; ++p) {
    const int cc = q + p * 4;
    op[(size_t)cc * N_NODES + c] = f2bf(sm[c][cc]);
  }
}

// ---------------------------------------------------------------------------
// Kernel B: Zb = S @ Xt^T, bf16 MFMA, 3-slot-ring deep pipeline.
// BM=256 (S rows), BN=128 (Xt rows), BK=64.  8 waves, wave grid 4m x 2n,
// per-wave 64x64 output (4x4 frags, 2 k-slices -> 32 MFMA/tile).
// LDS: 3 slots x (A 32KB + B 16KB) = 144 KB.  Per tile: vmcnt(6)+barrier,
// issue 6 gload_lds for tile t+2 (slot (t+2)%3), 2 phases x 16 MFMA.
// Read-side XOR swizzle (cbyte ^= (row&7)<<4) realized by pre-swizzled
// per-lane GLOBAL source addresses + linear gload_lds dest (G21 scheme).
// ---------------------------------------------------------------------------
__global__ __launch_bounds__(512) void diffuse_gemm_pipe(
    const u16* __restrict__ S, const u16* __restrict__ Xt,
    u16* __restrict__ Zb) {
  __shared__ __align__(16) u16 lds[3 * SLOT_U16];   // 144 KB
  const int tid = threadIdx.x;
  const int lane = tid & 63;
  const int w = tid >> 6;                 // wave 0..7
  // XCD-aware bijective swizzle (512 = 8*64)
  const int bid = blockIdx.x;
  const int sw = (bid & 7) * 64 + (bid >> 3);
  const int by = sw >> 5;                 // n-tile 0..15
  const int bx = sw & 31;                 // j-tile 0..31
  const int n0 = by * BM;
  const int j0 = bx * BN;

  // ---- staging maps: 48 chunks of 8 rows x 128 B; wave w owns chunks w*6+i.
  // LDS linear byte q = chunk*1024 + lane*16 holds logical row chunk*8+(l>>3),
  // swizzled col; so global col = 16*((l&7) ^ (l>>3)) bytes (uniform).
  const int lrow8 = lane >> 3;
  const int scol = 8 * ((lane & 7) ^ lrow8);      // elems
  const u16* gsrc[6];
  const u16* lbase[6];
#pragma unroll
  for (int i = 0; i < 6; ++i) {
    const int chunk = w * 6 + i;
    if (chunk < 32) {   // A chunk
      const int row = chunk * 8 + lrow8;          // 0..255
      gsrc[i] = S + (size_t)(n0 + row) * N_NODES + scol;
      lbase[i] = &lds[chunk * 512];               // wave-uniform
    } else {            // B chunk
      const int row = (chunk - 32) * 8 + lrow8;   // 0..127
      gsrc[i] = Xt + (size_t)(j0 + row) * N_NODES + scol;
      lbase[i] = &lds[BOFF_U16 + (chunk - 32) * 512];
    }
  }

  // ---- fragment read precompute
  const int wm = w >> 1, wn = w & 1;
  const int fr = lane & 15;
  const int khalf = lane >> 4;
  const int swz16 = (fr & 7) << 3;        // swizzle in u16 units

  f32x4 acc[4][4];
#pragma unroll
  for (int i = 0; i < 4; ++i)
#pragma unroll
    for (int j = 0; j < 4; ++j) acc[i][j] = (f32x4)0.f;

#define STAGE(tt)                                                         \
  {                                                                       \
    const int _s = (tt) % 3;                                              \
    _Pragma("unroll")                                                     \
    for (int i = 0; i < 6; ++i)                                           \
      gload16(gsrc[i] + (size_t)(tt) * 64,                                \
              (void*)(lbase[i] + _s * SLOT_U16));                         \
  }

#define COMPUTE(ss)                                                       \
  {                                                                       \
    const u16* sa = &lds[(ss) * SLOT_U16];                                \
    const u16* sb = sa + BOFF_U16;                                        \
    _Pragma("unroll")                                                     \
    for (int ks = 0; ks < 2; ++ks) {                                      \
      const int c16 = (ks * 32 + khalf * 8) ^ swz16;                      \
      bf16x8 a[4], b[4];                                                  \
      _Pragma("unroll")                                                   \
      for (int fm = 0; fm < 4; ++fm)                                      \
        a[fm] = *reinterpret_cast<const bf16x8*>(                         \
            &sa[(wm * 64 + fm * 16 + fr) * 64 + c16]);                    \
      _Pragma("unroll")                                                   \
      for (int fn = 0; fn < 4; ++fn)                                      \
        b[fn] = *reinterpret_cast<const bf16x8*>(                         \
            &sb[(wn * 64 + fn * 16 + fr) * 64 + c16]);                    \
      __builtin_amdgcn_s_setprio(1);                                      \
      _Pragma("unroll")                                                   \
      for (int fm = 0; fm < 4; ++fm)                                      \
        _Pragma("unroll")                                                 \
        for (int fn = 0; fn < 4; ++fn)                                    \
          acc[fm][fn] = __builtin_amdgcn_mfma_f32_16x16x32_bf16(          \
              a[fm], b[fn], acc[fm][fn], 0, 0, 0);                        \
      __builtin_amdgcn_s_setprio(0);                                      \
    }                                                                     \
  }

  // prologue: tiles 0,1 -> slots 0,1
  STAGE(0);
  STAGE(1);

  int s = 0;
  for (int t = 0; t < 62; ++t) {
    asm volatile("s_waitcnt vmcnt(6)" ::: "memory");   // tile t landed
    __builtin_amdgcn_s_barrier();                      // ... for ALL waves
    __builtin_amdgcn_sched_barrier(0);
    STAGE(t + 2);                                      // slot (t+2)%3: WAR-safe
    COMPUTE(s);
    s = (s == 2) ? 0 : s + 1;
  }
  // t = 62 (tile 63 still in flight)
  asm volatile("s_waitcnt vmcnt(6)" ::: "memory");
  __builtin_amdgcn_s_barrier();
  __builtin_amdgcn_sched_barrier(0);
  COMPUTE(s);
  s = (s == 2) ? 0 : s + 1;
  // t = 63 (drain)
  asm volatile("s_waitcnt vmcnt(0)" ::: "memory");
  __builtin_amdgcn_s_barrier();
  __builtin_amdgcn_sched_barrier(0);
  COMPUTE(s);

  // epilogue: C/D layout col=lane&15, row=(lane>>4)*4+reg
  const int crow = (lane >> 4) * 4;
  const int ccol = lane & 15;
#pragma unroll
  for (int fm = 0; fm < 4; ++fm) {
    const int nrow = n0 + wm * 64 + fm * 16 + crow;
#pragma unroll
    for (int fn = 0; fn < 4; ++fn) {
      const int jcol = j0 + wn * 64 + fn * 16 + ccol;
#pragma unroll
      for (int r = 0; r < 4; ++r)
        Zb[(size_t)(nrow + r) * N_NODES + jcol] = f2bf(acc[fm][fn][r]);
    }
  }
#undef STAGE
#undef COMPUTE
}

// ---------------------------------------------------------------------------
// Kernel C: per-node MFMA GEMM (unchanged from R3).
// ---------------------------------------------------------------------------
__global__ __launch_bounds__(256) void node_gemm_mfma(
    const float* __restrict__ x, const u16* __restrict__ Zb,
    const float* __restrict__ E, const float* __restrict__ wp,
    const float* __restrict__ bp, float* __restrict__ out) {
  __shared__ __align__(16) u16 Wt[2][64][LKP];
  __shared__ __align__(16) u16 Axz[2][64][LKP];
  __shared__ float biasS[2][64];
  __shared__ float EnS[2][EMB];
  const int n0 = blockIdx.x * 2;
  const int t = threadIdx.x;
  const int lane = t & 63;
  const int w = t >> 6;
  if (t < 2 * EMB) EnS[t / EMB][t % EMB] = E[n0 * EMB + t];
  __syncthreads();
  float en0[EMB], en1[EMB];
#pragma unroll
  for (int d = 0; d < EMB; ++d) { en0[d] = EnS[0][d]; en1[d] = EnS[1][d]; }

  if (t < 128) {
    const int nn = t >> 6, o = t & 63;
    float b = 0.f;
#pragma unroll
    for (int d = 0; d < EMB; ++d) b += EnS[nn][d] * bp[d * CO + o];
    biasS[nn][o] = b;
  }

  const float4* wp4 = reinterpret_cast<const float4*>(wp);
#pragma unroll
  for (int p = 0; p < 8; ++p) {
    const int e4 = p * 256 + t;
    const int ki = e4 >> 4, o4 = e4 & 15;
    float a0x = 0.f, a0y = 0.f, a0z = 0.f, a0w = 0.f;
    float a1x = 0.f, a1y = 0.f, a1z = 0.f, a1w = 0.f;
#pragma unroll
    for (int d = 0; d < EMB; ++d) {
      const float4 wv = wp4[d * 2048 + e4];
      a0x += en0[d] * wv.x; a0y += en0[d] * wv.y;
      a0z += en0[d] * wv.z; a0w += en0[d] * wv.w;
      a1x += en1[d] * wv.x; a1y += en1[d] * wv.y;
      a1z += en1[d] * wv.z; a1w += en1[d] * wv.w;
    }
    Wt[0][o4 * 4 + 0][ki] = f2bf(a0x); Wt[0][o4 * 4 + 1][ki] = f2bf(a0y);
    Wt[0][o4 * 4 + 2][ki] = f2bf(a0z); Wt[0][o4 * 4 + 3][ki] = f2bf(a0w);
    Wt[1][o4 * 4 + 0][ki] = f2bf(a1x); Wt[1][o4 * 4 + 1][ki] = f2bf(a1y);
    Wt[1][o4 * 4 + 2][ki] = f2bf(a1z); Wt[1][o4 * 4 + 3][ki] = f2bf(a1w);
  }

#pragma unroll
  for (int nn = 0; nn < 2; ++nn) {
    const int ng = n0 + nn;
#pragma unroll
    for (int pb = 0; pb < 4; ++pb) {
      const int b = pb * 16 + (t >> 4);
      const int i0 = (t & 15) * 4;
      const float4 xv = *reinterpret_cast<const float4*>(
          &x[(size_t)b * (N_NODES * CI) + (size_t)ng * CI + i0]);
      ushort4 uv;
      uv.x = f2bf(xv.x); uv.y = f2bf(xv.y); uv.z = f2bf(xv.z); uv.w = f2bf(xv.w);
      *reinterpret_cast<ushort4*>(&Axz[nn][b][i0]) = uv;
    }
#pragma unroll
    for (int pz = 0; pz < 4; ++pz) {
      const int t4 = pz * 256 + t;
      const int b = t4 >> 4, c0 = (t4 & 15) * 4;
      const ushort4 zv = *reinterpret_cast<const ushort4*>(
          &Zb[(size_t)ng * N_NODES + t4 * 4]);
      *reinterpret_cast<ushort4*>(&Axz[nn][b][64 + c0]) = zv;
    }
  }
  __syncthreads();

  const int nn = w >> 1, bh = w & 1;
  const int fr = lane & 15, fk = (lane >> 4) * 8;
  f32x4 acc[2][4];
#pragma unroll
  for (int m = 0; m < 2; ++m)
#pragma unroll
    for (int n = 0; n < 4; ++n) acc[m][n] = (f32x4)0.f;

#pragma unroll
  for (int kk = 0; kk < 4; ++kk) {
    bf16x8 a[2], b[4];
#pragma unroll
    for (int m = 0; m < 2; ++m)
      a[m] = *reinterpret_cast<const bf16x8*>(
          &Axz[nn][bh * 32 + m * 16 + fr][kk * 32 + fk]);
#pragma unroll
    for (int n = 0; n < 4; ++n)
      b[n] = *reinterpret_cast<const bf16x8*>(
          &Wt[nn][n * 16 + fr][kk * 32 + fk]);
#pragma unroll
    for (int m = 0; m < 2; ++m)
#pragma unroll
      for (int n = 0; n < 4; ++n)
        acc[m][n] = __builtin_amdgcn_mfma_f32_16x16x32_bf16(
            a[m], b[n], acc[m][n], 0, 0, 0);
  }

  const int crow = (lane >> 4) * 4;
  const int ccol = lane & 15;
  const int ng = n0 + nn;
#pragma unroll
  for (int m = 0; m < 2; ++m) {
#pragma unroll
    for (int n = 0; n < 4; ++n) {
      const int o = n * 16 + ccol;
      const float bv = biasS[nn][o];
#pragma unroll
      for (int r = 0; r < 4; ++r) {
        const int b = bh * 32 + m * 16 + crow + r;
        out[(size_t)b * (N_NODES * CI) + (size_t)ng * CI + o] =
            acc[m][n][r] + bv;
      }
    }
  }
}

// ---------------------------------------------------------------------------
extern "C" void kernel_launch(void* const* d_in, const int* in_sizes, int n_in,
                              void* d_out, int out_size, void* d_ws, size_t ws_size,
                              hipStream_t stream) {
  const float* x  = (const float*)d_in[0];   // [64, 4096, 64]
  const float* E  = (const float*)d_in[1];   // [4096, 10]
  const float* wp = (const float*)d_in[2];   // [10, 2, 64, 64]
  const float* bp = (const float*)d_in[3];   // [10, 64]
  float* out = (float*)d_out;                // [64, 4096, 64]
  const size_t MAT = (size_t)N_NODES * N_NODES;
  u16* Sb = (u16*)d_ws;                      // bf16 S    (33.5 MB)
  u16* Xt = Sb + MAT;                        // bf16 X^T  (33.5 MB)
  u16* Zb = Xt + MAT;                        // bf16 Z    (33.5 MB)

  support_softmax<<<N_NODES / 4, 256, 0, stream>>>(E, Sb);
  convert_x<<<dim3(BATCH_SZ, N_NODES / 64), 256, 0, stream>>>(x, Xt);
  diffuse_gemm_pipe<<<512, 512, 0, stream>>>(Sb, Xt, Zb);
  node_gemm_mfma<<<N_NODES / 2, 256, 0, stream>>>(x, Zb, E, wp, bp, out);
}